// Round 8
// baseline (11828.705 us; speedup 1.0000x reference)
//
#include <hip/hip_runtime.h>
#include <hip/hip_bf16.h>

#define T_LEN 2048
#define DIN   128
#define NH    256
#define G4H   1024
#define DOUT  128

typedef float  f32x4  __attribute__((ext_vector_type(4)));
typedef __bf16 bf16x8 __attribute__((ext_vector_type(8)));
typedef unsigned int u32;
typedef u32 u32x4 __attribute__((ext_vector_type(4)));

#define AL32(p) __hip_atomic_load((const u32*)(p), __ATOMIC_RELAXED, __HIP_MEMORY_SCOPE_AGENT)
#define CBAR()  asm volatile("" ::: "memory")

static __device__ __forceinline__ float sigf(float x) { return 1.0f / (1.0f + __expf(-x)); }
static __device__ __forceinline__ float tanh_(float x) {
    float ax = fabsf(x);
    float e  = __expf(-2.0f * ax);
    float r  = (1.0f - e) / (1.0f + e);
    return x < 0.0f ? -r : r;
}

// ws: u32 hb[2][4][16][256] = 128 KiB. Word = (tag<<16) | bf16bits(h), tag(t) = t+1
// (so poison 0xAAAA and zero never match; NO memset needed -- h_0 self-published
// with tag 1 by each block at kernel start). 32-bit stores are single-copy atomic
// -> tag+payload consistent. Slot = t&1; max inter-participant drift is 1 step
// (each step consumes ALL producers' h), so slot reuse is safe (r6/r7-proven).
//
// Round-8 exchange: producers DOUBLE-publish each word: `sc0` store (XCD-L2 copy,
// fast path for same-XCD readers -- ids {bg,bg+8,bg+16,bg+24} are same-XCD under
// round-robin) + `sc0 sc1` store (MALL copy, correct for ANY placement).
// Consumers poll with `sc0` loads (~300cy L2 round trip); a thread that retries
// >96x (cross-XCD: its L2 line can be stale forever) stickily falls back to
// `sc0 sc1` loads (MALL, r7 behavior). Correctness is placement-independent;
// only speed depends on placement. buffer_inv sc1 at start drops stale L2 lines
// from prior launches; buffer_wbl2 sc1 at exit flushes dirty lines.
//
// Grid 32 x 256 thr; bg = id&7 (>=4 idle), cb = id>>3. 4 waves/block; wave w owns
// units [cb*64 + w*16, +16) x 4 gates, weights register-resident (~192 VGPR).
// MFMA 16x16x32 maps (verified r1/r3/r6/r7): A row=l&15(batch), A k=(l>>4)*8+e;
// B col=l&15(unit), k same; C col=l&15, row=4*(l>>4)+reg -> lane-local update.

// 16 x dwordx4 tagged loads of this thread's h row-slice + single vmcnt(0).
// Offsets: kt*128 + {0,16}, kt=0..7. Outputs data-depend on the asm -> the
// consuming VALU checks cannot be hoisted above the waitcnt.
#define POLL_ASM(SC) \
    asm volatile( \
        "global_load_dwordx4 %0, %16, off " SC "\n\t" \
        "global_load_dwordx4 %1, %16, off offset:16 " SC "\n\t" \
        "global_load_dwordx4 %2, %16, off offset:128 " SC "\n\t" \
        "global_load_dwordx4 %3, %16, off offset:144 " SC "\n\t" \
        "global_load_dwordx4 %4, %16, off offset:256 " SC "\n\t" \
        "global_load_dwordx4 %5, %16, off offset:272 " SC "\n\t" \
        "global_load_dwordx4 %6, %16, off offset:384 " SC "\n\t" \
        "global_load_dwordx4 %7, %16, off offset:400 " SC "\n\t" \
        "global_load_dwordx4 %8, %16, off offset:512 " SC "\n\t" \
        "global_load_dwordx4 %9, %16, off offset:528 " SC "\n\t" \
        "global_load_dwordx4 %10, %16, off offset:640 " SC "\n\t" \
        "global_load_dwordx4 %11, %16, off offset:656 " SC "\n\t" \
        "global_load_dwordx4 %12, %16, off offset:768 " SC "\n\t" \
        "global_load_dwordx4 %13, %16, off offset:784 " SC "\n\t" \
        "global_load_dwordx4 %14, %16, off offset:896 " SC "\n\t" \
        "global_load_dwordx4 %15, %16, off offset:912 " SC "\n\t" \
        "s_waitcnt vmcnt(0)" \
        : "=&v"(Q0), "=&v"(Q1), "=&v"(Q2), "=&v"(Q3), \
          "=&v"(Q4), "=&v"(Q5), "=&v"(Q6), "=&v"(Q7), \
          "=&v"(Q8), "=&v"(Q9), "=&v"(Q10), "=&v"(Q11), \
          "=&v"(Q12), "=&v"(Q13), "=&v"(Q14), "=&v"(Q15) \
        : "v"(rp) : "memory")

// double-publish 4 tagged words (rows lk*4 + 0..3, stride 1024 B)
#define PUB(WP, W0, W1, W2, W3) \
    asm volatile( \
        "global_store_dword %4, %0, off sc0\n\t" \
        "global_store_dword %4, %1, off offset:1024 sc0\n\t" \
        "global_store_dword %4, %2, off offset:2048 sc0\n\t" \
        "global_store_dword %4, %3, off offset:3072 sc0\n\t" \
        "global_store_dword %4, %0, off sc0 sc1\n\t" \
        "global_store_dword %4, %1, off offset:1024 sc0 sc1\n\t" \
        "global_store_dword %4, %2, off offset:2048 sc0 sc1\n\t" \
        "global_store_dword %4, %3, off offset:3072 sc0 sc1" \
        :: "v"(W0), "v"(W1), "v"(W2), "v"(W3), "v"(WP) : "memory")

#define HMFMA(QA, QB, KT) { \
    union { u32 u[4]; bf16x8 v; } fa; \
    fa.u[0] = (QA[0] & 0xffffu) | (QA[1] << 16); \
    fa.u[1] = (QA[2] & 0xffffu) | (QA[3] << 16); \
    fa.u[2] = (QB[0] & 0xffffu) | (QB[1] << 16); \
    fa.u[3] = (QB[2] & 0xffffu) | (QB[3] << 16); \
    acc[0] = __builtin_amdgcn_mfma_f32_16x16x32_bf16(fa.v, whf[KT][0], acc[0], 0, 0, 0); \
    acc[1] = __builtin_amdgcn_mfma_f32_16x16x32_bf16(fa.v, whf[KT][1], acc[1], 0, 0, 0); \
    acc[2] = __builtin_amdgcn_mfma_f32_16x16x32_bf16(fa.v, whf[KT][2], acc[2], 0, 0, 0); \
    acc[3] = __builtin_amdgcn_mfma_f32_16x16x32_bf16(fa.v, whf[KT][3], acc[3], 0, 0, 0); }

__global__ __launch_bounds__(256, 1) void lstm_scan(
    const float* __restrict__ x,   const float* __restrict__ Wx,
    const float* __restrict__ Wh,  const float* __restrict__ bias,
    const float* __restrict__ fcw, const float* __restrict__ fcb,
    float* __restrict__ out, void* __restrict__ ws)
{
    const int id = blockIdx.x;
    const int bg = id & 7;
    if (bg >= 4) return;
    const int cb  = id >> 3;            // 0..3
    const int tid = threadIdx.x;
    const int w   = tid >> 6;           // wave 0..3
    const int l   = tid & 63;
    const int lu  = l & 15;
    const int lk  = l >> 4;
    const int ub  = cb * 64 + w * 16;   // first unit owned by this wave

    u32* hb = (u32*)ws;                 // [slot][bg][row16][col256]
    #define PANEL(s, b) ((size_t)(((s) * 4 + (b))) * 4096)

    __shared__ float hsm[16 * 256];

    // drop stale clean L2 lines from prior launches (tags from the previous
    // run would otherwise be served by this XCD's L2 forever)
    asm volatile("buffer_inv sc1" ::: "memory");

    // ---- self-publish h_0 = 0 with tag 1 (slot 0) ----
    {
        u32* wp0 = hb + PANEL(0, bg) + (lk * 4) * 256 + ub + lu;
        const u32 t1 = 1u << 16;
        PUB(wp0, t1, t1, t1, t1);
    }

    // ---- register-resident weights (bf16 B-fragments, this wave's 64 gate-cols) ----
    bf16x8 whf[8][4];
    #pragma unroll
    for (int kt = 0; kt < 8; ++kt)
        #pragma unroll
        for (int g = 0; g < 4; ++g) {
            bf16x8 f;
            #pragma unroll
            for (int e = 0; e < 8; ++e)
                f[e] = (__bf16)Wh[(kt * 32 + lk * 8 + e) * G4H + g * 256 + ub + lu];
            whf[kt][g] = f;
        }
    bf16x8 wxf[4][4];
    #pragma unroll
    for (int kt = 0; kt < 4; ++kt)
        #pragma unroll
        for (int g = 0; g < 4; ++g) {
            bf16x8 f;
            #pragma unroll
            for (int e = 0; e < 8; ++e)
                f[e] = (__bf16)Wx[(kt * 32 + lk * 8 + e) * G4H + g * 256 + ub + lu];
            wxf[kt][g] = f;
        }
    float bv[4];
    #pragma unroll
    for (int g = 0; g < 4; ++g) bv[g] = bias[g * 256 + ub + lu];

    const float* xrow = x + (size_t)(bg * 16 + lu) * (size_t)(T_LEN * DIN);

    float cc[4] = {0.f, 0.f, 0.f, 0.f};
    float hv[4] = {0.f, 0.f, 0.f, 0.f};
    int fast = 1;                       // sticky per-thread modality

    for (int t = 0; t < T_LEN; ++t) {
        // ---- x_t: load f32, convert, 16 MFMAs (independent of h) ----
        const float* xp = xrow + (size_t)t * DIN;
        f32x4 acc[4];
        #pragma unroll
        for (int g = 0; g < 4; ++g) { f32x4 a = {bv[g], bv[g], bv[g], bv[g]}; acc[g] = a; }
        #pragma unroll
        for (int kt = 0; kt < 4; ++kt) {
            f32x4 u = *(const f32x4*)(xp + kt * 32 + lk * 8);
            f32x4 v = *(const f32x4*)(xp + kt * 32 + lk * 8 + 4);
            bf16x8 a;
            #pragma unroll
            for (int e = 0; e < 4; ++e) { a[e] = (__bf16)u[e]; a[e + 4] = (__bf16)v[e]; }
            #pragma unroll
            for (int g = 0; g < 4; ++g)
                acc[g] = __builtin_amdgcn_mfma_f32_16x16x32_bf16(a, wxf[kt][g], acc[g], 0, 0, 0);
        }

        // ---- poll h_t (tag t+1, slot t&1): this thread's row slice, 64 words ----
        const u32* rp = hb + PANEL(t & 1, bg) + lu * 256 + lk * 8;
        u32x4 Q0, Q1, Q2, Q3, Q4, Q5, Q6, Q7, Q8, Q9, Q10, Q11, Q12, Q13, Q14, Q15;
        if (fast) POLL_ASM("sc0"); else POLL_ASM("sc0 sc1");
        {
            const u32 want = (u32)(t + 1) << 16;
            const u32x4 w4 = {want, want, want, want};
            int tries = 0;
            for (;;) {
                u32x4 b = (Q0 ^ w4);
                b |= (Q1 ^ w4);  b |= (Q2 ^ w4);  b |= (Q3 ^ w4);
                b |= (Q4 ^ w4);  b |= (Q5 ^ w4);  b |= (Q6 ^ w4);
                b |= (Q7 ^ w4);  b |= (Q8 ^ w4);  b |= (Q9 ^ w4);
                b |= (Q10 ^ w4); b |= (Q11 ^ w4); b |= (Q12 ^ w4);
                b |= (Q13 ^ w4); b |= (Q14 ^ w4); b |= (Q15 ^ w4);
                u32 bad = (b[0] | b[1] | b[2] | b[3]) & 0xFFFF0000u;
                if (!bad) break;
                if (fast && ++tries > 96) fast = 0;   // cross-XCD: L2 line stale forever
                if (fast) POLL_ASM("sc0"); else POLL_ASM("sc0 sc1");
            }
        }

        // ---- unpack + 32 wh MFMAs ----
        HMFMA(Q0,  Q1,  0)  HMFMA(Q2,  Q3,  1)
        HMFMA(Q4,  Q5,  2)  HMFMA(Q6,  Q7,  3)
        HMFMA(Q8,  Q9,  4)  HMFMA(Q10, Q11, 5)
        HMFMA(Q12, Q13, 6)  HMFMA(Q14, Q15, 7)

        // ---- gates + cell update (lane-local); double-publish h_{t+1}, tag t+2 ----
        u32* wp = hb + PANEL((t + 1) & 1, bg) + (lk * 4) * 256 + ub + lu;
        const u32 tg = (u32)(t + 2) << 16;
        u32 wv[4];
        #pragma unroll
        for (int r = 0; r < 4; ++r) {
            float iv = sigf(acc[0][r]);
            float fv = sigf(acc[1][r]);
            float gv = tanh_(acc[2][r]);
            float ov = sigf(acc[3][r]);
            cc[r] = fv * cc[r] + iv * gv;
            hv[r] = ov * tanh_(cc[r]);
            union { __bf16 b; unsigned short u; } cv; cv.b = (__bf16)hv[r];
            wv[r] = tg | (u32)cv.u;
        }
        PUB(wp, wv[0], wv[1], wv[2], wv[3]);
    }

    // ---- FC epilogue: poll h_T (tag T_LEN+1, slot 0) via MALL loads, GEMV ----
    const u32* fb = hb + PANEL(T_LEN & 1, bg);
    for (int i = tid; i < 4096; i += 256) {
        u32 qv;
        do { qv = AL32(fb + i); CBAR(); } while ((qv >> 16) != (u32)(T_LEN + 1));
        union { unsigned short u; __bf16 b; } cv; cv.u = (unsigned short)(qv & 0xffff);
        hsm[i] = (float)cv.b;
    }
    __syncthreads();
    // patch own 64 cols with full-precision f32 h
    #pragma unroll
    for (int r = 0; r < 4; ++r) hsm[(lk * 4 + r) * 256 + ub + lu] = hv[r];
    __syncthreads();

    for (int idx = tid; idx < 16 * 32; idx += 256) {
        int m = idx >> 5;
        int d = cb * 32 + (idx & 31);
        float s = fcb[d];
        for (int j = 0; j < NH; ++j) s += hsm[m * 256 + j] * fcw[j * DOUT + d];
        out[(bg * 16 + m) * DOUT + d] = s;
    }

    // flush dirty exchange lines so the next launch's poison fully takes effect
    asm volatile("s_waitcnt vmcnt(0)\n\tbuffer_wbl2 sc1\n\ts_waitcnt vmcnt(0)" ::: "memory");
    #undef PANEL
}

extern "C" void kernel_launch(void* const* d_in, const int* in_sizes, int n_in,
                              void* d_out, int out_size, void* d_ws, size_t ws_size,
                              hipStream_t stream) {
    (void)in_sizes; (void)n_in; (void)ws_size; (void)out_size;
    const float* x   = (const float*)d_in[0];
    const float* Wx  = (const float*)d_in[1];
    const float* Wh  = (const float*)d_in[2];
    const float* b   = (const float*)d_in[3];
    const float* fcw = (const float*)d_in[4];
    const float* fcb = (const float*)d_in[5];
    float* out = (float*)d_out;

    // no memset needed: tags are 1-based, poison 0xAAAA never matches,
    // h_0 is self-published by each block.
    hipLaunchKernelGGL(lstm_scan, dim3(32), dim3(256), 0, stream,
                       x, Wx, Wh, b, fcw, fcb, out, d_ws);
}